// Round 3
// baseline (1696.063 us; speedup 1.0000x reference)
//
#include <hip/hip_runtime.h>

using u16 = unsigned short;
using u32 = unsigned int;
typedef __bf16 bf16x8 __attribute__((ext_vector_type(8)));
typedef float  f32x4  __attribute__((ext_vector_type(4)));
typedef u16    u16x8  __attribute__((ext_vector_type(8)));

__device__ __forceinline__ float b2f(u16 u) { return __uint_as_float(((u32)u) << 16); }
__device__ __forceinline__ u16 f2b(float f) {
    u32 u = __float_as_uint(f);
    u32 r = (u + 0x7fffu + ((u >> 16) & 1u)) >> 16;   // RNE
    return (u16)r;
}
__device__ __forceinline__ float sigm(float x)      { return 1.f / (1.f + __expf(-x)); }
__device__ __forceinline__ float tanh_fast(float x) { return 1.f - 2.f / (__expf(2.f * x) + 1.f); }

// async global->LDS, 16B per lane; LDS dest is wave-uniform base + lane*16
__device__ __forceinline__ void glds16(const void* g, void* l) {
    __builtin_amdgcn_global_load_lds(
        (const __attribute__((address_space(1))) void*)g,
        (__attribute__((address_space(3))) void*)l, 16, 0, 0);
}

// xp layout: chunk16(g, tl, bg, w, quad, col) = ((g*TL+tl)*512 + bg*16 + w*4 + quad)*16 + col
// within chunk: hh*4+rg   (cell = w*32+hh*16+col, batch = bg*16+quad*4+rg)

// ---------------------------------------------------------------------------
// prep: dtype detect + 20-tensor convert + b_x transpose to bf16 [t][b][d]
// ---------------------------------------------------------------------------
#define NSEG 20
struct CvtArgs {
    const void* src[NSEG];
    u32 cnt[NSEG];
    u32 off[NSEG];
    u32 blk0[NSEG];
};

__global__ __launch_bounds__(256) void prep_k(
    CvtArgs a, const void* bx_src, const void* hf_src,
    u16* arena, u16* bxT, int* flag, u16* zp, int CV)
{
    const int tid = threadIdx.x;
    __shared__ int s_isb;
    if (tid == 0) s_isb = 1;
    __syncthreads();
    if (tid < 128) {
        float v = b2f(((const u16*)hf_src)[tid]);
        if (!(v >= 0.0f && v <= 1.0f)) atomicAnd(&s_isb, 0);
    }
    __syncthreads();
    const int isb = s_isb;
    const u32 blk = blockIdx.x;

    if (blk < (u32)CV) {
        int seg = 0;
#pragma unroll
        for (int i = 1; i < NSEG; ++i) if (blk >= a.blk0[i]) seg = i;
        const u32 base = (blk - a.blk0[seg]) * 2048u + tid * 8u;
        const u32 cnt = a.cnt[seg];
        u16* dst = arena + a.off[seg];
        if (isb) {
            const u16* s = (const u16*)a.src[seg];
            if (base + 8 <= cnt)      *(uint4*)(dst + base) = *(const uint4*)(s + base);
            else if (base < cnt)      for (u32 i = base; i < cnt; ++i) dst[i] = s[i];
        } else {
            const float* s = (const float*)a.src[seg];
            if (base + 8 <= cnt) {
                float4 f0 = *(const float4*)(s + base);
                float4 f1 = *(const float4*)(s + base + 4);
                u16x8 o;
                o[0]=f2b(f0.x); o[1]=f2b(f0.y); o[2]=f2b(f0.z); o[3]=f2b(f0.w);
                o[4]=f2b(f1.x); o[5]=f2b(f1.y); o[6]=f2b(f1.z); o[7]=f2b(f1.w);
                *(uint4*)(dst + base) = __builtin_bit_cast(uint4, o);
            } else if (base < cnt) {
                for (u32 i = base; i < cnt; ++i) dst[i] = f2b(s[i]);
            }
        }
    } else if (blk < (u32)CV + 15000u) {
        u32 i = (blk - CV) * 256 + tid;
        u32 dc = i % 25u, r = i / 25u;              // r = b*300+t
        u32 t = r % 300u, b = r / 300u;
        size_t so = (size_t)r * 200 + dc * 8;
        size_t dofs = ((size_t)t * 512 + b) * 200 + dc * 8;
        u16x8 o;
        if (isb) {
            o = __builtin_bit_cast(u16x8, *(const uint4*)((const u16*)bx_src + so));
        } else {
            const float* s = (const float*)bx_src + so;
            float4 f0 = *(const float4*)s, f1 = *(const float4*)(s + 4);
            o[0]=f2b(f0.x); o[1]=f2b(f0.y); o[2]=f2b(f0.z); o[3]=f2b(f0.w);
            o[4]=f2b(f1.x); o[5]=f2b(f1.y); o[6]=f2b(f1.z); o[7]=f2b(f1.w);
        }
        *(uint4*)(bxT + dofs) = __builtin_bit_cast(uint4, o);
    } else {
        if (tid < 128) zp[tid] = 0;
        if (tid == 0) *flag = isb;
    }
}

// ---------------------------------------------------------------------------
// Fused fwd+bwd input projection body: xp{f,b} = A * W{f,b}^T + bias
// glds staging: LDS linear [128][32] u16 (64B rows); slot swizzle
//   slot s of row r holds k-chunk ch = s ^ ((r>>1)&3)   (2-way banks = free)
// ---------------------------------------------------------------------------
template<int K>
__device__ __forceinline__ void proj_body(
    int pblk, void* smraw, const u16* __restrict__ zpage,
    const u16* __restrict__ A0,
    const u16* __restrict__ W0, const u16* __restrict__ W1,
    const u16* __restrict__ bih0, const u16* __restrict__ bhh0,
    const u16* __restrict__ bih1, const u16* __restrict__ bhh1,
    u16* __restrict__ C0, u16* __restrict__ C1,
    int TL, int mb_f, int mb_b, int tb0_f, int tb0_b)
{
    constexpr int nK = (K + 31) / 32;
    u16* AsL = (u16*)smraw;           // 8192 B
    u16* BsL = (u16*)smraw + 4096;    // 8192 B

    const int tid = threadIdx.x;
    const int ntile = pblk & 7;
    const int dir = ntile >> 2, gnt = ntile & 3;
    const int mtile = (dir ? mb_b : mb_f) + (pblk >> 3);
    const int tb0 = dir ? tb0_b : tb0_f;
    const u16* W   = dir ? W1 : W0;
    const u16* bih = dir ? bih1 : bih0;
    const u16* bhh = dir ? bhh1 : bhh0;
    u16* C = dir ? C1 : C0;
    const int m0 = mtile * 128, n0 = gnt * 128;
    const int lane = tid & 63, wid = tid >> 6;
    const int wrow = wid >> 1, wcol = wid & 1;
    const int col = lane & 15, quad = lane >> 4;

    f32x4 acc[4][4] = {};

    for (int kt = 0; kt < nK; ++kt) {
        const int k0 = kt * 32;
#pragma unroll
        for (int it = 0; it < 2; ++it) {
            const int idx = it * 256 + tid;
            const int row = idx >> 2;
            const int ch = (idx & 3) ^ ((row >> 1) & 3);
            const int k = k0 + ch * 8;
            const bool ok = (K % 32 == 0) || (k + 8 <= K);
            const u16* ga = ok ? (A0 + (size_t)(m0 + row) * K + k) : zpage;
            const u16* gb = ok ? (W  + (size_t)(n0 + row) * K + k) : zpage;
            const int lb = (it * 256 + wid * 64) * 8;   // wave-uniform, u16 units
            glds16(ga, AsL + lb);
            glds16(gb, BsL + lb);
        }
        __syncthreads();

        bf16x8 af[4], bf[4];
#pragma unroll
        for (int mt = 0; mt < 4; ++mt) {
            const int r = wrow * 64 + mt * 16 + col;
            const int sl = quad ^ ((r >> 1) & 3);
            af[mt] = __builtin_bit_cast(bf16x8, *(uint4*)(AsL + r * 32 + sl * 8));
        }
#pragma unroll
        for (int nt = 0; nt < 4; ++nt) {
            const int r = wcol * 64 + nt * 16 + col;
            const int sl = quad ^ ((r >> 1) & 3);
            bf[nt] = __builtin_bit_cast(bf16x8, *(uint4*)(BsL + r * 32 + sl * 8));
        }
#pragma unroll
        for (int mt = 0; mt < 4; ++mt)
#pragma unroll
            for (int nt = 0; nt < 4; ++nt)
                acc[mt][nt] = __builtin_amdgcn_mfma_f32_16x16x32_bf16(af[mt], bf[nt], acc[mt][nt], 0, 0, 0);
        __syncthreads();
    }

    const int tl = (mtile >> 2) - tb0;
#pragma unroll
    for (int mt = 0; mt < 4; ++mt) {
        const int bg = ((m0 + wrow * 64 + mt * 16) >> 4) & 31;
#pragma unroll
        for (int j = 0; j < 2; ++j) {
            const int w = wcol * 2 + j;
            const int nA = n0 + w * 32 + col;
            const float bA = b2f(bih[nA]) + b2f(bhh[nA]);
            const float bB = b2f(bih[nA + 16]) + b2f(bhh[nA + 16]);
            u16x8 o;
#pragma unroll
            for (int rg = 0; rg < 4; ++rg) {
                o[rg]     = f2b(acc[mt][2 * j][rg] + bA);
                o[4 + rg] = f2b(acc[mt][2 * j + 1][rg] + bB);
            }
            size_t idx16 = (((size_t)gnt * TL + tl) * 512 + bg * 16 + w * 4 + quad) * 16 + col;
            *(uint4*)(C + idx16 * 8) = __builtin_bit_cast(uint4, o);
        }
    }
}

template<int K>
__global__ __launch_bounds__(256) void proj_k(
    const u16* __restrict__ zpage,
    const u16* __restrict__ A0,
    const u16* __restrict__ W0, const u16* __restrict__ W1,
    const u16* __restrict__ bih0, const u16* __restrict__ bhh0,
    const u16* __restrict__ bih1, const u16* __restrict__ bhh1,
    u16* __restrict__ C0, u16* __restrict__ C1,
    int TL, int mb_f, int mb_b, int tb0_f, int tb0_b)
{
    __shared__ alignas(16) char smraw[20480];
    proj_body<K>(blockIdx.x, smraw, zpage, A0, W0, W1, bih0, bhh0, bih1, bhh1,
                 C0, C1, TL, mb_f, mb_b, tb0_f, tb0_b);
}

// ---------------------------------------------------------------------------
// LSTM recurrence body.  Single barrier per step:
//   - gbuf handoff (MFMA scatter -> dense read) is INTRA-WAVE (dense thread
//     tid reads cells tid>>1 in [w*32, w*32+32), written by lanes of the same
//     wave; gbuf rows are wave-private) -> no barrier needed, LDS pipe is
//     in-order per wave.
//   - hist handoff (dense write -> next step's B-fragment read) is cross-wave
//     -> one __syncthreads() per step.
//   - flush reads the whole hist ring -> extra barrier after flush steps.
// setprio(1): recurrence waves win issue arbitration vs co-resident proj.
// ---------------------------------------------------------------------------
__device__ __forceinline__ void lstm_body(
    int lblk, void* smraw,
    const u16* __restrict__ xp_f, const u16* __restrict__ xp_b,
    const u16* __restrict__ whh_f, const u16* __restrict__ whh_b,
    const u16* __restrict__ hf,
    u16* __restrict__ out_f, u16* __restrict__ out_b,
    u16* __restrict__ hstate, float* __restrict__ cstate,
    int ostride_f, int ostride_b, int ooff_f, int ooff_b,
    int S, int s0, int tb0_f, int tb0_b, int first, int TL)
{
    __builtin_amdgcn_s_setprio(1);

    const int tid = threadIdx.x;
    const int lane = tid & 63, w = tid >> 6;
    const int col = lane & 15, quad = lane >> 4;
    const int dir = lblk >> 7;
    const int bq = lblk & 127, b0 = bq * 4;
    const int bg = bq >> 2, qb = bq & 3;

    const u16* xp  = dir ? xp_b  : xp_f;
    const u16* whh = dir ? whh_b : whh_f;
    u16* outp      = dir ? out_b : out_f;
    const int ostride = dir ? ostride_b : ostride_f;
    const int ooff    = dir ? ooff_b    : ooff_f;
    const int tb0     = dir ? tb0_b     : tb0_f;

    struct LS { u16 hist[8][4][136]; float gbuf[4][520]; };
    LS& sm = *(LS*)smraw;
    auto& hist = sm.hist;   // h ring: slot s = h entering step s (mod 8)
    auto& gbuf = sm.gbuf;   // raw gate sums, [batch][gate-row], wave-private rows

    // w_hh A-fragments: tile a=(g*2+cb) covers gate-rows g*128+w*32+cb*16+col
    bf16x8 wf[8][4];
#pragma unroll
    for (int a = 0; a < 8; ++a) {
        int g = a >> 1, cb = a & 1;
        int n = g * 128 + w * 32 + cb * 16 + col;
#pragma unroll
        for (int ks = 0; ks < 4; ++ks)
            wf[a][ks] = __builtin_bit_cast(bf16x8,
                *(const uint4*)(whh + (size_t)n * 128 + ks * 32 + quad * 8));
    }

    // dense assignment: lane = (cell, batches bh, bh+1)
    const int cell = tid >> 1;
    const int bh = (tid & 1) * 2;

    float c2[2];
    if (first) {
        for (int i = tid; i < 512; i += 256)
            hist[0][i >> 7][i & 127] = hf[i & 127];
        float v = b2f(hf[cell]);
        c2[0] = v; c2[1] = v;
    } else {
        for (int i = tid; i < 512; i += 256)
            hist[0][i >> 7][i & 127] =
                hstate[(size_t)dir * 65536 + (b0 + (i >> 7)) * 128 + (i & 127)];
#pragma unroll
        for (int j = 0; j < 2; ++j)
            c2[j] = cstate[(size_t)dir * 65536 + (b0 + bh + j) * 128 + cell];
    }
    __syncthreads();

    // xp dense address (4B per gate: 2 batches of one cell)
    const size_t inv = ((size_t)(bg * 16 + (cell >> 5) * 4 + qb)) * 128
                     + (size_t)(cell & 15) * 8 + ((cell >> 4) & 1) * 4 + bh;
    auto xload = [&](int sl, u32* q) {
        int t = dir ? (299 - (s0 + sl)) : (s0 + sl);
        int tl = t - tb0;
#pragma unroll
        for (int g = 0; g < 4; ++g)
            q[g] = *(const u32*)(xp + (size_t)(g * TL + tl) * 65536 + inv);
    };

    u32 xq[4];
    xload(0, xq);

#pragma unroll 1
    for (int sl = 0; sl < S; ++sl) {
        const int cur = sl & 7, nxt = (sl + 1) & 7;

        u32 xn[4];
        if (sl + 1 < S) xload(sl + 1, xn);

        // h fragments (B operand: n=batch col&3, k=cell)
        bf16x8 hfr[4];
#pragma unroll
        for (int ks = 0; ks < 4; ++ks)
            hfr[ks] = __builtin_bit_cast(bf16x8, *(uint4*)&hist[cur][col & 3][ks * 32 + quad * 8]);

        f32x4 acc[8] = {};
#pragma unroll
        for (int ks = 0; ks < 4; ++ks)
#pragma unroll
            for (int a = 0; a < 8; ++a)
                acc[a] = __builtin_amdgcn_mfma_f32_16x16x32_bf16(wf[a][ks], hfr[ks], acc[a], 0, 0, 0);

        // scatter raw gate sums to LDS (valid cols 0..3 only; rows wave-private)
        if (col < 4) {
#pragma unroll
            for (int a = 0; a < 8; ++a) {
                int g = a >> 1, cb = a & 1;
                int row = g * 128 + w * 32 + cb * 16 + quad * 4;
                *(f32x4*)&gbuf[col][row] = acc[a];
            }
        }
        // NO barrier: gbuf producer/consumer are the same wave (in-order LDS)

        // dense phase: 1 cell x 2 batches per lane
        float h2[2];
#pragma unroll
        for (int j = 0; j < 2; ++j) {
            float gi = gbuf[bh + j][0 * 128 + cell];
            float gf = gbuf[bh + j][1 * 128 + cell];
            float gc = gbuf[bh + j][2 * 128 + cell];
            float go = gbuf[bh + j][3 * 128 + cell];
            u16 xi = (u16)(xq[0] >> (j * 16));
            u16 xf = (u16)(xq[1] >> (j * 16));
            u16 xc = (u16)(xq[2] >> (j * 16));
            u16 xo = (u16)(xq[3] >> (j * 16));
            float ig = sigm(gi + b2f(xi));
            float fg = sigm(gf + b2f(xf));
            float cg = tanh_fast(gc + b2f(xc));
            float og = sigm(go + b2f(xo));
            float cn = fg * c2[j] + ig * cg;
            c2[j] = cn;
            h2[j] = og * tanh_fast(cn);
        }
        hist[nxt][bh + 0][cell] = f2b(h2[0]);
        hist[nxt][bh + 1][cell] = f2b(h2[1]);

#pragma unroll
        for (int g = 0; g < 4; ++g) xq[g] = xn[g];
        __syncthreads();   // hist[nxt] ready for all waves

        if ((sl & 7) == 7) {           // flush outputs of steps fb*8 .. fb*8+7
            const int fb = sl >> 3;
            const int fs = tid >> 5, be = (tid >> 3) & 3, ch = tid & 7;
            const int j = (fs + 7) & 7;
            const int s = s0 + fb * 8 + j;
            const int t = dir ? (299 - s) : s;
            uint4 v0 = *(uint4*)&hist[fs][be][ch * 16];
            uint4 v1 = *(uint4*)&hist[fs][be][ch * 16 + 8];
            u16* dst = outp + ((size_t)t * 512 + b0 + be) * ostride + ooff + ch * 16;
            *(uint4*)dst = v0;
            *(uint4*)(dst + 8) = v1;
            __syncthreads();           // protect hist ring from next step's dense
        }
    }

    const int rem = S & 7;
    if (rem) {
        const int base_s = s0 + (S & ~7);
        const int fs = tid >> 5, be = (tid >> 3) & 3, ch = tid & 7;
        const int j = (fs + 7) & 7;
        if (j < rem) {
            const int s = base_s + j;
            const int t = dir ? (299 - s) : s;
            uint4 v0 = *(uint4*)&hist[fs][be][ch * 16];
            uint4 v1 = *(uint4*)&hist[fs][be][ch * 16 + 8];
            u16* dst = outp + ((size_t)t * 512 + b0 + be) * ostride + ooff + ch * 16;
            *(uint4*)dst = v0;
            *(uint4*)(dst + 8) = v1;
        }
    }

    for (int i = tid; i < 512; i += 256)
        hstate[(size_t)dir * 65536 + (b0 + (i >> 7)) * 128 + (i & 127)] =
            hist[S & 7][i >> 7][i & 127];
#pragma unroll
    for (int j = 0; j < 2; ++j)
        cstate[(size_t)dir * 65536 + (b0 + bh + j) * 128 + cell] = c2[j];
    __builtin_amdgcn_s_setprio(0);
}

// ---------------------------------------------------------------------------
// Fused pipeline launch: blocks 0..255 run lstm(chunk c) reading xp[par];
// blocks 256.. run proj(chunk c+1) writing xp[1-par].
// min-waves 3 -> up to 1 lstm + 2 proj blocks per CU (VGPR 100 <= 170).
// ---------------------------------------------------------------------------
template<int K>
__global__ __launch_bounds__(256, 3) void fused_k(
    const u16* __restrict__ zpage,
    // lstm (current chunk)
    const u16* __restrict__ xp_f, const u16* __restrict__ xp_b,
    const u16* __restrict__ whh_f, const u16* __restrict__ whh_b,
    const u16* __restrict__ hf,
    u16* __restrict__ out_f, u16* __restrict__ out_b,
    u16* __restrict__ hstate, float* __restrict__ cstate,
    int ostride_f, int ostride_b, int ooff_f, int ooff_b,
    int S, int s0, int ltb0_f, int ltb0_b, int first, int TL,
    // proj (next chunk)
    const u16* __restrict__ A0,
    const u16* __restrict__ W0, const u16* __restrict__ W1,
    const u16* __restrict__ bih0, const u16* __restrict__ bhh0,
    const u16* __restrict__ bih1, const u16* __restrict__ bhh1,
    u16* __restrict__ C0, u16* __restrict__ C1,
    int pmb_f, int pmb_b, int ptb0_f, int ptb0_b)
{
    __shared__ alignas(16) char smraw[20480];
    if (blockIdx.x < 256) {
        lstm_body(blockIdx.x, smraw, xp_f, xp_b, whh_f, whh_b, hf, out_f, out_b,
                  hstate, cstate, ostride_f, ostride_b, ooff_f, ooff_b,
                  S, s0, ltb0_f, ltb0_b, first, TL);
    } else {
        proj_body<K>(blockIdx.x - 256, smraw, zpage, A0, W0, W1, bih0, bhh0, bih1, bhh1,
                     C0, C1, TL, pmb_f, pmb_b, ptb0_f, ptb0_b);
    }
}

// ---------------------------------------------------------------------------
// Fused head GEMM + max-pool + linear + b_y.  One block per batch b.
// glds staging with the same linear+swizzle layout as proj.
// ---------------------------------------------------------------------------
__global__ __launch_bounds__(256) void headpool_k(
    const u16* __restrict__ zpage,
    const u16* __restrict__ bxT, const u16* __restrict__ W,
    const u16* __restrict__ F1, const u16* __restrict__ R1,
    const u16* __restrict__ HF, const u16* __restrict__ W2,
    const u16* __restrict__ B2, const int* __restrict__ BY,
    void* __restrict__ out, const int* __restrict__ flag)
{
    constexpr int K = 456, nK = 15;
    __shared__ alignas(16) u16 AsL[4096];
    __shared__ alignas(16) u16 BsL[4096];
    __shared__ float redL[8][128];
    __shared__ float pmax[128];

    const int b = blockIdx.x;
    const int tid = threadIdx.x;
    const int lane = tid & 63, wid = tid >> 6;
    const int wrow = wid >> 1, wcol = wid & 1;
    const int col = lane & 15, quad = lane >> 4;

    float lm[4] = { -1e30f, -1e30f, -1e30f, -1e30f };

    for (int mtile = 0; mtile < 3; ++mtile) {
        f32x4 acc[4][4] = {};
        for (int kt = 0; kt < nK; ++kt) {
            const int k0 = kt * 32;
#pragma unroll
            for (int it = 0; it < 2; ++it) {
                const int idx = it * 256 + tid;
                const int row = idx >> 2;
                const int ch = (idx & 3) ^ ((row >> 1) & 3);
                const int k = k0 + ch * 8;
                const int t = mtile * 128 + row;
                const u16* ga = zpage;
                const u16* gb = zpage;
                if (k + 8 <= K) {
                    gb = W + (size_t)row * K + k;
                    if (t < 300) {
                        if (k < 128)      ga = (t == 0)   ? (HF + k) : (F1 + ((size_t)t * 512 + b) * 128 + k);
                        else if (k < 328) ga = bxT + ((size_t)t * 512 + b) * 200 + (k - 128);
                        else { int j = k - 328;
                               ga = (t == 299) ? (HF + j) : (R1 + ((size_t)(298 - t) * 512 + b) * 128 + j); }
                    }
                }
                const int lb = (it * 256 + wid * 64) * 8;  // wave-uniform
                glds16(ga, AsL + lb);
                glds16(gb, BsL + lb);
            }
            __syncthreads();

            bf16x8 af[4], bf[4];
#pragma unroll
            for (int mt = 0; mt < 4; ++mt) {
                const int r = wrow * 64 + mt * 16 + col;
                const int sl = quad ^ ((r >> 1) & 3);
                af[mt] = __builtin_bit_cast(bf16x8, *(uint4*)(AsL + r * 32 + sl * 8));
            }
#pragma unroll
            for (int nt = 0; nt < 4; ++nt) {
                const int r = wcol * 64 + nt * 16 + col;
                const int sl = quad ^ ((r >> 1) & 3);
                bf[nt] = __builtin_bit_cast(bf16x8, *(uint4*)(BsL + r * 32 + sl * 8));
            }
#pragma unroll
            for (int mt = 0; mt < 4; ++mt)
#pragma unroll
                for (int nt = 0; nt < 4; ++nt)
                    acc[mt][nt] = __builtin_amdgcn_mfma_f32_16x16x32_bf16(af[mt], bf[nt], acc[mt][nt], 0, 0, 0);
            __syncthreads();
        }
#pragma unroll
        for (int nt = 0; nt < 4; ++nt)
#pragma unroll
            for (int mt = 0; mt < 4; ++mt)
#pragma unroll
                for (int rg = 0; rg < 4; ++rg) {
                    int t = mtile * 128 + wrow * 64 + mt * 16 + quad * 4 + rg;
                    if (t < 300) lm[nt] = fmaxf(lm[nt], tanh_fast(acc[mt][nt][rg]));
                }
    }

#pragma unroll
    for (int nt = 0; nt < 4; ++nt)
        redL[wrow * 4 + quad][wcol * 64 + nt * 16 + col] = lm[nt];
    __syncthreads();
    if (tid < 128) {
        float m = redL[0][tid];
#pragma unroll
        for (int r = 1; r < 8; ++r) m = fmaxf(m, redL[r][tid]);
        pmax[tid] = m;
    }
    __syncthreads();
    const bool isb = (*flag != 0);
    if (tid < 4) {
        float s = b2f(B2[tid]);
#pragma unroll 8
        for (int k = 0; k < 128; ++k) s += pmax[k] * b2f(W2[tid * 128 + k]);
        if (isb) ((u16*)out)[b * 4 + tid] = f2b(s);
        else     ((float*)out)[b * 4 + tid] = s;
    }
    if (tid == 4) {
        if (isb) ((u16*)out)[2048 + b] = f2b((float)BY[b]);
        else     ((float*)out)[2048 + b] = (float)BY[b];
    }
}

__global__ void diag_k(void* out, float code) {
    ((float*)out)[1] = code;
    ((u16*)out)[0] = f2b(code);
}

// ---------------------------------------------------------------------------
extern "C" void kernel_launch(void* const* d_in, const int* in_sizes, int n_in,
                              void* d_out, int out_size, void* d_ws, size_t ws_size,
                              hipStream_t stream)
{
    const int* b_y = (const int*)d_in[1];

    static const u32 CNT21[21] = {
        30720000, 128,
        102400, 65536, 512, 512,
        102400, 65536, 512, 512,
        131072, 65536, 512, 512,
        131072, 65536, 512, 512,
        58368, 512, 4 };
    static const int SRC_IDX[21] = { 0, 2, 3,4,5,6, 7,8,9,10, 11,12,13,14, 15,16,17,18, 19, 20, 21 };
    u32 off[21];
    u32 o = 0;
    for (int i = 0; i < 21; ++i) { off[i] = o; o += (CNT21[i] + 7u) & ~7u; }
    const size_t ARENA_BYTES = 63024640;
    const size_t PIPE_OFF    = ARENA_BYTES + 256;

    const size_t SZ_Y0 = 78643200;
    const size_t SZ_H  = 39321600;
    auto needD = [&](int CSv) -> size_t {   // double-buffered xp (pipelined)
        return PIPE_OFF + 4ull * (size_t)CSv * 524288ull + SZ_Y0 + 2 * SZ_H + 786432 + 1024;
    };
    auto needS = [&](int CSv) -> size_t {   // single-buffered xp (serial fallback)
        return PIPE_OFF + 2ull * (size_t)CSv * 524288ull + SZ_Y0 + 2 * SZ_H + 786432 + 1024;
    };
    int CS = 0, dbuf = 1;
    if      (ws_size >= needD(75)) CS = 75;
    else if (ws_size >= needD(50)) CS = 50;
    else if (ws_size >= needD(25)) CS = 25;
    else if (ws_size >= needD(5))  CS = 5;
    else {
        dbuf = 0;
        if      (ws_size >= needS(25)) CS = 25;
        else if (ws_size >= needS(5))  CS = 5;
    }
    if (CS == 0) {
        diag_k<<<1, 1, 0, stream>>>(d_out, (float)(1000 + (int)(ws_size >> 20)));
        return;
    }
    const int NC = 300 / CS;
    const size_t XPC = (size_t)CS * 524288ull;
    const size_t XPTOT = (dbuf ? 4 : 2) * XPC;

    char* ws = (char*)d_ws;
    u16* arena = (u16*)ws;
    int* flag  = (int*)(ws + ARENA_BYTES);
    char* pb = ws + PIPE_OFF;
    // xp parity buffers: [par][dir]
    u16* xc_f[2]; u16* xc_b[2];
    xc_f[0] = (u16*)(pb);
    xc_b[0] = (u16*)(pb + XPC);
    if (dbuf) { xc_f[1] = (u16*)(pb + 2 * XPC); xc_b[1] = (u16*)(pb + 3 * XPC); }
    else      { xc_f[1] = xc_f[0];              xc_b[1] = xc_b[0]; }
    u16* y0  = (u16*)(pb + XPTOT);
    u16* f1  = (u16*)(pb + XPTOT + SZ_Y0);
    u16* r1  = (u16*)(pb + XPTOT + SZ_Y0 + SZ_H);
    u16* hst = (u16*)(pb + XPTOT + SZ_Y0 + 2 * SZ_H);
    float* cst = (float*)(pb + XPTOT + SZ_Y0 + 2 * SZ_H + 262144);
    u16* zpg = (u16*)(pb + XPTOT + SZ_Y0 + 2 * SZ_H + 786432);

    const u16 *bxT = arena + off[0], *hf_a = arena + off[1];
    const u16 *wih_l0f = arena + off[2],  *whh_l0f = arena + off[3],  *bih_l0f = arena + off[4],  *bhh_l0f = arena + off[5];
    const u16 *wih_l0b = arena + off[6],  *whh_l0b = arena + off[7],  *bih_l0b = arena + off[8],  *bhh_l0b = arena + off[9];
    const u16 *wih_l1f = arena + off[10], *whh_l1f = arena + off[11], *bih_l1f = arena + off[12], *bhh_l1f = arena + off[13];
    const u16 *wih_l1b = arena + off[14], *whh_l1b = arena + off[15], *bih_l1b = arena + off[16], *bhh_l1b = arena + off[17];
    const u16 *wl1_a = arena + off[18], *wl2_a = arena + off[19], *bl2_a = arena + off[20];

    CvtArgs ca;
    u32 bk = 0;
    for (int i = 0; i < NSEG; ++i) {
        ca.src[i] = d_in[SRC_IDX[i + 1]];
        ca.cnt[i] = CNT21[i + 1];
        ca.off[i] = off[i + 1];
        ca.blk0[i] = bk;
        bk += (CNT21[i + 1] + 2047u) / 2048u;
    }
    prep_k<<<bk + 15000 + 1, 256, 0, stream>>>(ca, d_in[0], d_in[2],
                                               arena, (u16*)(arena + off[0]), flag, zpg, (int)bk);

    // ---- layer 0: pipeline proj(c+1) under lstm(c) ----
    proj_k<200><<<CS * 32, 256, 0, stream>>>(zpg, bxT, wih_l0f, wih_l0b,
        bih_l0f, bhh_l0f, bih_l0b, bhh_l0b, xc_f[0], xc_b[0], CS, 0, (300 - CS) * 4, 0, 300 - CS);
    for (int c = 0; c < NC; ++c) {
        const int par = dbuf ? (c & 1) : 0;
        const int nx  = dbuf ? (par ^ 1) : 0;
        const int tf0 = c * CS, tb0 = 300 - (c + 1) * CS;
        if (!dbuf && c > 0)
            proj_k<200><<<CS * 32, 256, 0, stream>>>(zpg, bxT, wih_l0f, wih_l0b,
                bih_l0f, bhh_l0f, bih_l0b, bhh_l0b, xc_f[0], xc_b[0], CS,
                tf0 * 4, tb0 * 4, tf0, tb0);
        const int dp = dbuf && (c + 1 < NC);
        const int ntf0 = (c + 1) * CS, ntb0 = 300 - (c + 2) * CS;
        fused_k<200><<<256 + (dp ? CS * 32 : 0), 256, 0, stream>>>(zpg,
            xc_f[par], xc_b[par], whh_l0f, whh_l0b, hf_a, y0, y0, hst, cst,
            256, 256, 0, 128, CS, c * CS, tf0, tb0, c == 0, CS,
            bxT, wih_l0f, wih_l0b, bih_l0f, bhh_l0f, bih_l0b, bhh_l0b,
            xc_f[nx], xc_b[nx], ntf0 * 4, ntb0 * 4, ntf0, ntb0);
    }

    // ---- layer 1 ----
    proj_k<256><<<CS * 32, 256, 0, stream>>>(zpg, y0, wih_l1f, wih_l1b,
        bih_l1f, bhh_l1f, bih_l1b, bhh_l1b, xc_f[0], xc_b[0], CS, 0, (300 - CS) * 4, 0, 300 - CS);
    for (int c = 0; c < NC; ++c) {
        const int par = dbuf ? (c & 1) : 0;
        const int nx  = dbuf ? (par ^ 1) : 0;
        const int tf0 = c * CS, tb0 = 300 - (c + 1) * CS;
        if (!dbuf && c > 0)
            proj_k<256><<<CS * 32, 256, 0, stream>>>(zpg, y0, wih_l1f, wih_l1b,
                bih_l1f, bhh_l1f, bih_l1b, bhh_l1b, xc_f[0], xc_b[0], CS,
                tf0 * 4, tb0 * 4, tf0, tb0);
        const int dp = dbuf && (c + 1 < NC);
        const int ntf0 = (c + 1) * CS, ntb0 = 300 - (c + 2) * CS;
        fused_k<256><<<256 + (dp ? CS * 32 : 0), 256, 0, stream>>>(zpg,
            xc_f[par], xc_b[par], whh_l1f, whh_l1b, hf_a, f1, r1, hst, cst,
            128, 128, 0, 0, CS, c * CS, tf0, tb0, c == 0, CS,
            y0, wih_l1f, wih_l1b, bih_l1f, bhh_l1f, bih_l1b, bhh_l1b,
            xc_f[nx], xc_b[nx], ntf0 * 4, ntb0 * 4, ntf0, ntb0);
    }

    headpool_k<<<512, 256, 0, stream>>>(zpg, bxT, wl1_a, f1, r1, hf_a, wl2_a, bl2_a, b_y, d_out, flag);
}

// Round 5
// 1142.699 us; speedup vs baseline: 1.4843x; 1.4843x over previous
//
#include <hip/hip_runtime.h>

using u16 = unsigned short;
using u32 = unsigned int;
typedef __bf16 bf16x8 __attribute__((ext_vector_type(8)));
typedef float  f32x4  __attribute__((ext_vector_type(4)));
typedef u16    u16x8  __attribute__((ext_vector_type(8)));

__device__ __forceinline__ float b2f(u16 u) { return __uint_as_float(((u32)u) << 16); }
__device__ __forceinline__ u16 f2b(float f) {
    u32 u = __float_as_uint(f);
    u32 r = (u + 0x7fffu + ((u >> 16) & 1u)) >> 16;   // RNE
    return (u16)r;
}
__device__ __forceinline__ float sigm(float x)      { return 1.f / (1.f + __expf(-x)); }
__device__ __forceinline__ float tanh_fast(float x) { return 1.f - 2.f / (__expf(2.f * x) + 1.f); }

// async global->LDS, 16B per lane; LDS dest is wave-uniform base + lane*16
__device__ __forceinline__ void glds16(const void* g, void* l) {
    __builtin_amdgcn_global_load_lds(
        (const __attribute__((address_space(1))) void*)g,
        (__attribute__((address_space(3))) void*)l, 16, 0, 0);
}

// xp layout: chunk16(g, tl, bg, w, quad, col) = ((g*TL+tl)*512 + bg*16 + w*4 + quad)*16 + col
// within chunk: hh*4+rg   (cell = w*32+hh*16+col, batch = bg*16+quad*4+rg)

// ---------------------------------------------------------------------------
// prep: dtype detect + 20-tensor convert + b_x transpose to bf16 [t][b][d]
// ---------------------------------------------------------------------------
#define NSEG 20
struct CvtArgs {
    const void* src[NSEG];
    u32 cnt[NSEG];
    u32 off[NSEG];
    u32 blk0[NSEG];
};

__global__ __launch_bounds__(256) void prep_k(
    CvtArgs a, const void* bx_src, const void* hf_src,
    u16* arena, u16* bxT, int* flag, u16* zp, int CV)
{
    const int tid = threadIdx.x;
    __shared__ int s_isb;
    if (tid == 0) s_isb = 1;
    __syncthreads();
    if (tid < 128) {
        float v = b2f(((const u16*)hf_src)[tid]);
        if (!(v >= 0.0f && v <= 1.0f)) atomicAnd(&s_isb, 0);
    }
    __syncthreads();
    const int isb = s_isb;
    const u32 blk = blockIdx.x;

    if (blk < (u32)CV) {
        int seg = 0;
#pragma unroll
        for (int i = 1; i < NSEG; ++i) if (blk >= a.blk0[i]) seg = i;
        const u32 base = (blk - a.blk0[seg]) * 2048u + tid * 8u;
        const u32 cnt = a.cnt[seg];
        u16* dst = arena + a.off[seg];
        if (isb) {
            const u16* s = (const u16*)a.src[seg];
            if (base + 8 <= cnt)      *(uint4*)(dst + base) = *(const uint4*)(s + base);
            else if (base < cnt)      for (u32 i = base; i < cnt; ++i) dst[i] = s[i];
        } else {
            const float* s = (const float*)a.src[seg];
            if (base + 8 <= cnt) {
                float4 f0 = *(const float4*)(s + base);
                float4 f1 = *(const float4*)(s + base + 4);
                u16x8 o;
                o[0]=f2b(f0.x); o[1]=f2b(f0.y); o[2]=f2b(f0.z); o[3]=f2b(f0.w);
                o[4]=f2b(f1.x); o[5]=f2b(f1.y); o[6]=f2b(f1.z); o[7]=f2b(f1.w);
                *(uint4*)(dst + base) = __builtin_bit_cast(uint4, o);
            } else if (base < cnt) {
                for (u32 i = base; i < cnt; ++i) dst[i] = f2b(s[i]);
            }
        }
    } else if (blk < (u32)CV + 15000u) {
        u32 i = (blk - CV) * 256 + tid;
        u32 dc = i % 25u, r = i / 25u;              // r = b*300+t
        u32 t = r % 300u, b = r / 300u;
        size_t so = (size_t)r * 200 + dc * 8;
        size_t dofs = ((size_t)t * 512 + b) * 200 + dc * 8;
        u16x8 o;
        if (isb) {
            o = __builtin_bit_cast(u16x8, *(const uint4*)((const u16*)bx_src + so));
        } else {
            const float* s = (const float*)bx_src + so;
            float4 f0 = *(const float4*)s, f1 = *(const float4*)(s + 4);
            o[0]=f2b(f0.x); o[1]=f2b(f0.y); o[2]=f2b(f0.z); o[3]=f2b(f0.w);
            o[4]=f2b(f1.x); o[5]=f2b(f1.y); o[6]=f2b(f1.z); o[7]=f2b(f1.w);
        }
        *(uint4*)(bxT + dofs) = __builtin_bit_cast(uint4, o);
    } else {
        if (tid < 128) zp[tid] = 0;
        if (tid == 0) *flag = isb;
    }
}

// ---------------------------------------------------------------------------
// Fused fwd+bwd input projection body: xp{f,b} = A * W{f,b}^T + bias
// glds staging: LDS linear [128][32] u16 (64B rows); slot swizzle
//   slot s of row r holds k-chunk ch = s ^ ((r>>1)&3)   (2-way banks = free)
// ---------------------------------------------------------------------------
template<int K>
__device__ __forceinline__ void proj_body(
    int pblk, void* smraw, const u16* __restrict__ zpage,
    const u16* __restrict__ A0,
    const u16* __restrict__ W0, const u16* __restrict__ W1,
    const u16* __restrict__ bih0, const u16* __restrict__ bhh0,
    const u16* __restrict__ bih1, const u16* __restrict__ bhh1,
    u16* __restrict__ C0, u16* __restrict__ C1,
    int TL, int mb_f, int mb_b, int tb0_f, int tb0_b)
{
    constexpr int nK = (K + 31) / 32;
    u16* AsL = (u16*)smraw;           // 8192 B
    u16* BsL = (u16*)smraw + 4096;    // 8192 B

    const int tid = threadIdx.x;
    const int ntile = pblk & 7;
    const int dir = ntile >> 2, gnt = ntile & 3;
    const int mtile = (dir ? mb_b : mb_f) + (pblk >> 3);
    const int tb0 = dir ? tb0_b : tb0_f;
    const u16* W   = dir ? W1 : W0;
    const u16* bih = dir ? bih1 : bih0;
    const u16* bhh = dir ? bhh1 : bhh0;
    u16* C = dir ? C1 : C0;
    const int m0 = mtile * 128, n0 = gnt * 128;
    const int lane = tid & 63, wid = tid >> 6;
    const int wrow = wid >> 1, wcol = wid & 1;
    const int col = lane & 15, quad = lane >> 4;

    f32x4 acc[4][4] = {};

    for (int kt = 0; kt < nK; ++kt) {
        const int k0 = kt * 32;
#pragma unroll
        for (int it = 0; it < 2; ++it) {
            const int idx = it * 256 + tid;
            const int row = idx >> 2;
            const int ch = (idx & 3) ^ ((row >> 1) & 3);
            const int k = k0 + ch * 8;
            const bool ok = (K % 32 == 0) || (k + 8 <= K);
            const u16* ga = ok ? (A0 + (size_t)(m0 + row) * K + k) : zpage;
            const u16* gb = ok ? (W  + (size_t)(n0 + row) * K + k) : zpage;
            const int lb = (it * 256 + wid * 64) * 8;   // wave-uniform, u16 units
            glds16(ga, AsL + lb);
            glds16(gb, BsL + lb);
        }
        __syncthreads();

        bf16x8 af[4], bf[4];
#pragma unroll
        for (int mt = 0; mt < 4; ++mt) {
            const int r = wrow * 64 + mt * 16 + col;
            const int sl = quad ^ ((r >> 1) & 3);
            af[mt] = __builtin_bit_cast(bf16x8, *(uint4*)(AsL + r * 32 + sl * 8));
        }
#pragma unroll
        for (int nt = 0; nt < 4; ++nt) {
            const int r = wcol * 64 + nt * 16 + col;
            const int sl = quad ^ ((r >> 1) & 3);
            bf[nt] = __builtin_bit_cast(bf16x8, *(uint4*)(BsL + r * 32 + sl * 8));
        }
#pragma unroll
        for (int mt = 0; mt < 4; ++mt)
#pragma unroll
            for (int nt = 0; nt < 4; ++nt)
                acc[mt][nt] = __builtin_amdgcn_mfma_f32_16x16x32_bf16(af[mt], bf[nt], acc[mt][nt], 0, 0, 0);
        __syncthreads();
    }

    const int tl = (mtile >> 2) - tb0;
#pragma unroll
    for (int mt = 0; mt < 4; ++mt) {
        const int bg = ((m0 + wrow * 64 + mt * 16) >> 4) & 31;
#pragma unroll
        for (int j = 0; j < 2; ++j) {
            const int w = wcol * 2 + j;
            const int nA = n0 + w * 32 + col;
            const float bA = b2f(bih[nA]) + b2f(bhh[nA]);
            const float bB = b2f(bih[nA + 16]) + b2f(bhh[nA + 16]);
            u16x8 o;
#pragma unroll
            for (int rg = 0; rg < 4; ++rg) {
                o[rg]     = f2b(acc[mt][2 * j][rg] + bA);
                o[4 + rg] = f2b(acc[mt][2 * j + 1][rg] + bB);
            }
            size_t idx16 = (((size_t)gnt * TL + tl) * 512 + bg * 16 + w * 4 + quad) * 16 + col;
            *(uint4*)(C + idx16 * 8) = __builtin_bit_cast(uint4, o);
        }
    }
}

template<int K>
__global__ __launch_bounds__(256) void proj_k(
    const u16* __restrict__ zpage,
    const u16* __restrict__ A0,
    const u16* __restrict__ W0, const u16* __restrict__ W1,
    const u16* __restrict__ bih0, const u16* __restrict__ bhh0,
    const u16* __restrict__ bih1, const u16* __restrict__ bhh1,
    u16* __restrict__ C0, u16* __restrict__ C1,
    int TL, int mb_f, int mb_b, int tb0_f, int tb0_b)
{
    __shared__ alignas(16) char smraw[20480];
    proj_body<K>(blockIdx.x, smraw, zpage, A0, W0, W1, bih0, bhh0, bih1, bhh1,
                 C0, C1, TL, mb_f, mb_b, tb0_f, tb0_b);
}

// ---------------------------------------------------------------------------
// LSTM recurrence body.  Single barrier per step:
//   - gbuf handoff (MFMA scatter -> dense read) is INTRA-WAVE (dense thread
//     tid reads cells tid>>1 in [w*32, w*32+32), written by lanes of the same
//     wave; gbuf rows are wave-private) -> no barrier needed, LDS pipe is
//     in-order per wave.
//   - hist handoff (dense write -> next step's B-fragment read) is cross-wave
//     -> one __syncthreads() per step.
//   - flush reads the whole hist ring -> extra barrier after flush steps.
// setprio(1): recurrence waves win issue arbitration vs co-resident proj.
// ---------------------------------------------------------------------------
__device__ __forceinline__ void lstm_body(
    int lblk, void* smraw,
    const u16* __restrict__ xp_f, const u16* __restrict__ xp_b,
    const u16* __restrict__ whh_f, const u16* __restrict__ whh_b,
    const u16* __restrict__ hf,
    u16* __restrict__ out_f, u16* __restrict__ out_b,
    u16* __restrict__ hstate, float* __restrict__ cstate,
    int ostride_f, int ostride_b, int ooff_f, int ooff_b,
    int S, int s0, int tb0_f, int tb0_b, int first, int TL)
{
    __builtin_amdgcn_s_setprio(1);

    const int tid = threadIdx.x;
    const int lane = tid & 63, w = tid >> 6;
    const int col = lane & 15, quad = lane >> 4;
    const int dir = lblk >> 7;
    const int bq = lblk & 127, b0 = bq * 4;
    const int bg = bq >> 2, qb = bq & 3;

    const u16* xp  = dir ? xp_b  : xp_f;
    const u16* whh = dir ? whh_b : whh_f;
    u16* outp      = dir ? out_b : out_f;
    const int ostride = dir ? ostride_b : ostride_f;
    const int ooff    = dir ? ooff_b    : ooff_f;
    const int tb0     = dir ? tb0_b     : tb0_f;

    struct LS { u16 hist[8][4][136]; float gbuf[4][520]; };
    LS& sm = *(LS*)smraw;
    auto& hist = sm.hist;   // h ring: slot s = h entering step s (mod 8)
    auto& gbuf = sm.gbuf;   // raw gate sums, [batch][gate-row], wave-private rows

    // w_hh A-fragments: tile a=(g*2+cb) covers gate-rows g*128+w*32+cb*16+col
    bf16x8 wf[8][4];
#pragma unroll
    for (int a = 0; a < 8; ++a) {
        int g = a >> 1, cb = a & 1;
        int n = g * 128 + w * 32 + cb * 16 + col;
#pragma unroll
        for (int ks = 0; ks < 4; ++ks)
            wf[a][ks] = __builtin_bit_cast(bf16x8,
                *(const uint4*)(whh + (size_t)n * 128 + ks * 32 + quad * 8));
    }

    // dense assignment: lane = (cell, batches bh, bh+1)
    const int cell = tid >> 1;
    const int bh = (tid & 1) * 2;

    float c2[2];
    if (first) {
        for (int i = tid; i < 512; i += 256)
            hist[0][i >> 7][i & 127] = hf[i & 127];
        float v = b2f(hf[cell]);
        c2[0] = v; c2[1] = v;
    } else {
        for (int i = tid; i < 512; i += 256)
            hist[0][i >> 7][i & 127] =
                hstate[(size_t)dir * 65536 + (b0 + (i >> 7)) * 128 + (i & 127)];
#pragma unroll
        for (int j = 0; j < 2; ++j)
            c2[j] = cstate[(size_t)dir * 65536 + (b0 + bh + j) * 128 + cell];
    }
    __syncthreads();

    // xp dense address (4B per gate: 2 batches of one cell)
    const size_t inv = ((size_t)(bg * 16 + (cell >> 5) * 4 + qb)) * 128
                     + (size_t)(cell & 15) * 8 + ((cell >> 4) & 1) * 4 + bh;
    auto xload = [&](int sl, u32* q) {
        int t = dir ? (299 - (s0 + sl)) : (s0 + sl);
        int tl = t - tb0;
#pragma unroll
        for (int g = 0; g < 4; ++g)
            q[g] = *(const u32*)(xp + (size_t)(g * TL + tl) * 65536 + inv);
    };

    u32 xq[4];
    xload(0, xq);

#pragma unroll 1
    for (int sl = 0; sl < S; ++sl) {
        const int cur = sl & 7, nxt = (sl + 1) & 7;

        u32 xn[4];
        if (sl + 1 < S) xload(sl + 1, xn);

        // h fragments (B operand: n=batch col&3, k=cell)
        bf16x8 hfr[4];
#pragma unroll
        for (int ks = 0; ks < 4; ++ks)
            hfr[ks] = __builtin_bit_cast(bf16x8, *(uint4*)&hist[cur][col & 3][ks * 32 + quad * 8]);

        f32x4 acc[8] = {};
#pragma unroll
        for (int ks = 0; ks < 4; ++ks)
#pragma unroll
            for (int a = 0; a < 8; ++a)
                acc[a] = __builtin_amdgcn_mfma_f32_16x16x32_bf16(wf[a][ks], hfr[ks], acc[a], 0, 0, 0);

        // scatter raw gate sums to LDS (valid cols 0..3 only; rows wave-private)
        if (col < 4) {
#pragma unroll
            for (int a = 0; a < 8; ++a) {
                int g = a >> 1, cb = a & 1;
                int row = g * 128 + w * 32 + cb * 16 + quad * 4;
                *(f32x4*)&gbuf[col][row] = acc[a];
            }
        }
        // NO barrier: gbuf producer/consumer are the same wave (in-order LDS)

        // dense phase: 1 cell x 2 batches per lane
        float h2[2];
#pragma unroll
        for (int j = 0; j < 2; ++j) {
            float gi = gbuf[bh + j][0 * 128 + cell];
            float gf = gbuf[bh + j][1 * 128 + cell];
            float gc = gbuf[bh + j][2 * 128 + cell];
            float go = gbuf[bh + j][3 * 128 + cell];
            u16 xi = (u16)(xq[0] >> (j * 16));
            u16 xf = (u16)(xq[1] >> (j * 16));
            u16 xc = (u16)(xq[2] >> (j * 16));
            u16 xo = (u16)(xq[3] >> (j * 16));
            float ig = sigm(gi + b2f(xi));
            float fg = sigm(gf + b2f(xf));
            float cg = tanh_fast(gc + b2f(xc));
            float og = sigm(go + b2f(xo));
            float cn = fg * c2[j] + ig * cg;
            c2[j] = cn;
            h2[j] = og * tanh_fast(cn);
        }
        hist[nxt][bh + 0][cell] = f2b(h2[0]);
        hist[nxt][bh + 1][cell] = f2b(h2[1]);

#pragma unroll
        for (int g = 0; g < 4; ++g) xq[g] = xn[g];
        __syncthreads();   // hist[nxt] ready for all waves

        if ((sl & 7) == 7) {           // flush outputs of steps fb*8 .. fb*8+7
            const int fb = sl >> 3;
            const int fs = tid >> 5, be = (tid >> 3) & 3, ch = tid & 7;
            const int j = (fs + 7) & 7;
            const int s = s0 + fb * 8 + j;
            const int t = dir ? (299 - s) : s;
            uint4 v0 = *(uint4*)&hist[fs][be][ch * 16];
            uint4 v1 = *(uint4*)&hist[fs][be][ch * 16 + 8];
            u16* dst = outp + ((size_t)t * 512 + b0 + be) * ostride + ooff + ch * 16;
            *(uint4*)dst = v0;
            *(uint4*)(dst + 8) = v1;
            __syncthreads();           // protect hist ring from next step's dense
        }
    }

    const int rem = S & 7;
    if (rem) {
        const int base_s = s0 + (S & ~7);
        const int fs = tid >> 5, be = (tid >> 3) & 3, ch = tid & 7;
        const int j = (fs + 7) & 7;
        if (j < rem) {
            const int s = base_s + j;
            const int t = dir ? (299 - s) : s;
            uint4 v0 = *(uint4*)&hist[fs][be][ch * 16];
            uint4 v1 = *(uint4*)&hist[fs][be][ch * 16 + 8];
            u16* dst = outp + ((size_t)t * 512 + b0 + be) * ostride + ooff + ch * 16;
            *(uint4*)dst = v0;
            *(uint4*)(dst + 8) = v1;
        }
    }

    for (int i = tid; i < 512; i += 256)
        hstate[(size_t)dir * 65536 + (b0 + (i >> 7)) * 128 + (i & 127)] =
            hist[S & 7][i >> 7][i & 127];
#pragma unroll
    for (int j = 0; j < 2; ++j)
        cstate[(size_t)dir * 65536 + (b0 + bh + j) * 128 + cell] = c2[j];
    __builtin_amdgcn_s_setprio(0);
}

// ---------------------------------------------------------------------------
// Fused pipeline launch: blocks 0..255 run lstm(chunk c) reading xp[par];
// blocks 256.. run proj(chunk c+1) writing xp[1-par].
// launch_bounds(256,2): VGPR cap ~128 -> lstm's ~100-reg body does NOT spill
// (min-waves 3 capped at 84 and spilled in the 75-step serial loop: R3
// regression, WRITE_SIZE +7.7MB of scratch).
// ---------------------------------------------------------------------------
template<int K>
__global__ __launch_bounds__(256, 2) void fused_k(
    const u16* __restrict__ zpage,
    // lstm (current chunk)
    const u16* __restrict__ xp_f, const u16* __restrict__ xp_b,
    const u16* __restrict__ whh_f, const u16* __restrict__ whh_b,
    const u16* __restrict__ hf,
    u16* __restrict__ out_f, u16* __restrict__ out_b,
    u16* __restrict__ hstate, float* __restrict__ cstate,
    int ostride_f, int ostride_b, int ooff_f, int ooff_b,
    int S, int s0, int ltb0_f, int ltb0_b, int first, int TL,
    // proj (next chunk)
    const u16* __restrict__ A0,
    const u16* __restrict__ W0, const u16* __restrict__ W1,
    const u16* __restrict__ bih0, const u16* __restrict__ bhh0,
    const u16* __restrict__ bih1, const u16* __restrict__ bhh1,
    u16* __restrict__ C0, u16* __restrict__ C1,
    int pmb_f, int pmb_b, int ptb0_f, int ptb0_b)
{
    __shared__ alignas(16) char smraw[20480];
    if (blockIdx.x < 256) {
        lstm_body(blockIdx.x, smraw, xp_f, xp_b, whh_f, whh_b, hf, out_f, out_b,
                  hstate, cstate, ostride_f, ostride_b, ooff_f, ooff_b,
                  S, s0, ltb0_f, ltb0_b, first, TL);
    } else {
        proj_body<K>(blockIdx.x - 256, smraw, zpage, A0, W0, W1, bih0, bhh0, bih1, bhh1,
                     C0, C1, TL, pmb_f, pmb_b, ptb0_f, ptb0_b);
    }
}

// ---------------------------------------------------------------------------
// Fused head GEMM + max-pool + linear + b_y.  One block per batch b.
// glds staging with the same linear+swizzle layout as proj.
// ---------------------------------------------------------------------------
__global__ __launch_bounds__(256) void headpool_k(
    const u16* __restrict__ zpage,
    const u16* __restrict__ bxT, const u16* __restrict__ W,
    const u16* __restrict__ F1, const u16* __restrict__ R1,
    const u16* __restrict__ HF, const u16* __restrict__ W2,
    const u16* __restrict__ B2, const int* __restrict__ BY,
    void* __restrict__ out, const int* __restrict__ flag)
{
    constexpr int K = 456, nK = 15;
    __shared__ alignas(16) u16 AsL[4096];
    __shared__ alignas(16) u16 BsL[4096];
    __shared__ float redL[8][128];
    __shared__ float pmax[128];

    const int b = blockIdx.x;
    const int tid = threadIdx.x;
    const int lane = tid & 63, wid = tid >> 6;
    const int wrow = wid >> 1, wcol = wid & 1;
    const int col = lane & 15, quad = lane >> 4;

    float lm[4] = { -1e30f, -1e30f, -1e30f, -1e30f };

    for (int mtile = 0; mtile < 3; ++mtile) {
        f32x4 acc[4][4] = {};
        for (int kt = 0; kt < nK; ++kt) {
            const int k0 = kt * 32;
#pragma unroll
            for (int it = 0; it < 2; ++it) {
                const int idx = it * 256 + tid;
                const int row = idx >> 2;
                const int ch = (idx & 3) ^ ((row >> 1) & 3);
                const int k = k0 + ch * 8;
                const int t = mtile * 128 + row;
                const u16* ga = zpage;
                const u16* gb = zpage;
                if (k + 8 <= K) {
                    gb = W + (size_t)row * K + k;
                    if (t < 300) {
                        if (k < 128)      ga = (t == 0)   ? (HF + k) : (F1 + ((size_t)t * 512 + b) * 128 + k);
                        else if (k < 328) ga = bxT + ((size_t)t * 512 + b) * 200 + (k - 128);
                        else { int j = k - 328;
                               ga = (t == 299) ? (HF + j) : (R1 + ((size_t)(298 - t) * 512 + b) * 128 + j); }
                    }
                }
                const int lb = (it * 256 + wid * 64) * 8;  // wave-uniform
                glds16(ga, AsL + lb);
                glds16(gb, BsL + lb);
            }
            __syncthreads();

            bf16x8 af[4], bf[4];
#pragma unroll
            for (int mt = 0; mt < 4; ++mt) {
                const int r = wrow * 64 + mt * 16 + col;
                const int sl = quad ^ ((r >> 1) & 3);
                af[mt] = __builtin_bit_cast(bf16x8, *(uint4*)(AsL + r * 32 + sl * 8));
            }
#pragma unroll
            for (int nt = 0; nt < 4; ++nt) {
                const int r = wcol * 64 + nt * 16 + col;
                const int sl = quad ^ ((r >> 1) & 3);
                bf[nt] = __builtin_bit_cast(bf16x8, *(uint4*)(BsL + r * 32 + sl * 8));
            }
#pragma unroll
            for (int mt = 0; mt < 4; ++mt)
#pragma unroll
                for (int nt = 0; nt < 4; ++nt)
                    acc[mt][nt] = __builtin_amdgcn_mfma_f32_16x16x32_bf16(af[mt], bf[nt], acc[mt][nt], 0, 0, 0);
            __syncthreads();
        }
#pragma unroll
        for (int nt = 0; nt < 4; ++nt)
#pragma unroll
            for (int mt = 0; mt < 4; ++mt)
#pragma unroll
                for (int rg = 0; rg < 4; ++rg) {
                    int t = mtile * 128 + wrow * 64 + mt * 16 + quad * 4 + rg;
                    if (t < 300) lm[nt] = fmaxf(lm[nt], tanh_fast(acc[mt][nt][rg]));
                }
    }

#pragma unroll
    for (int nt = 0; nt < 4; ++nt)
        redL[wrow * 4 + quad][wcol * 64 + nt * 16 + col] = lm[nt];
    __syncthreads();
    if (tid < 128) {
        float m = redL[0][tid];
#pragma unroll
        for (int r = 1; r < 8; ++r) m = fmaxf(m, redL[r][tid]);
        pmax[tid] = m;
    }
    __syncthreads();
    const bool isb = (*flag != 0);
    if (tid < 4) {
        float s = b2f(B2[tid]);
#pragma unroll 8
        for (int k = 0; k < 128; ++k) s += pmax[k] * b2f(W2[tid * 128 + k]);
        if (isb) ((u16*)out)[b * 4 + tid] = f2b(s);
        else     ((float*)out)[b * 4 + tid] = s;
    }
    if (tid == 4) {
        if (isb) ((u16*)out)[2048 + b] = f2b((float)BY[b]);
        else     ((float*)out)[2048 + b] = (float)BY[b];
    }
}

__global__ void diag_k(void* out, float code) {
    ((float*)out)[1] = code;
    ((u16*)out)[0] = f2b(code);
}

// ---------------------------------------------------------------------------
extern "C" void kernel_launch(void* const* d_in, const int* in_sizes, int n_in,
                              void* d_out, int out_size, void* d_ws, size_t ws_size,
                              hipStream_t stream)
{
    const int* b_y = (const int*)d_in[1];

    static const u32 CNT21[21] = {
        30720000, 128,
        102400, 65536, 512, 512,
        102400, 65536, 512, 512,
        131072, 65536, 512, 512,
        131072, 65536, 512, 512,
        58368, 512, 4 };
    static const int SRC_IDX[21] = { 0, 2, 3,4,5,6, 7,8,9,10, 11,12,13,14, 15,16,17,18, 19, 20, 21 };
    u32 off[21];
    u32 o = 0;
    for (int i = 0; i < 21; ++i) { off[i] = o; o += (CNT21[i] + 7u) & ~7u; }
    const size_t ARENA_BYTES = 63024640;
    const size_t PIPE_OFF    = ARENA_BYTES + 256;

    const size_t SZ_Y0 = 78643200;
    const size_t SZ_H  = 39321600;
    auto needD = [&](int CSv) -> size_t {   // double-buffered xp (pipelined)
        return PIPE_OFF + 4ull * (size_t)CSv * 524288ull + SZ_Y0 + 2 * SZ_H + 786432 + 1024;
    };
    auto needS = [&](int CSv) -> size_t {   // single-buffered xp (serial fallback)
        return PIPE_OFF + 2ull * (size_t)CSv * 524288ull + SZ_Y0 + 2 * SZ_H + 786432 + 1024;
    };
    int CS = 0, dbuf = 1;
    if      (ws_size >= needD(75)) CS = 75;
    else if (ws_size >= needD(50)) CS = 50;
    else if (ws_size >= needD(25)) CS = 25;
    else if (ws_size >= needD(5))  CS = 5;
    else {
        dbuf = 0;
        if      (ws_size >= needS(25)) CS = 25;
        else if (ws_size >= needS(5))  CS = 5;
    }
    if (CS == 0) {
        diag_k<<<1, 1, 0, stream>>>(d_out, (float)(1000 + (int)(ws_size >> 20)));
        return;
    }
    const int NC = 300 / CS;
    const size_t XPC = (size_t)CS * 524288ull;
    const size_t XPTOT = (dbuf ? 4 : 2) * XPC;

    char* ws = (char*)d_ws;
    u16* arena = (u16*)ws;
    int* flag  = (int*)(ws + ARENA_BYTES);
    char* pb = ws + PIPE_OFF;
    // xp parity buffers: [par][dir]
    u16* xc_f[2]; u16* xc_b[2];
    xc_f[0] = (u16*)(pb);
    xc_b[0] = (u16*)(pb + XPC);
    if (dbuf) { xc_f[1] = (u16*)(pb + 2 * XPC); xc_b[1] = (u16*)(pb + 3 * XPC); }
    else      { xc_f[1] = xc_f[0];              xc_b[1] = xc_b[0]; }
    u16* y0  = (u16*)(pb + XPTOT);
    u16* f1  = (u16*)(pb + XPTOT + SZ_Y0);
    u16* r1  = (u16*)(pb + XPTOT + SZ_Y0 + SZ_H);
    u16* hst = (u16*)(pb + XPTOT + SZ_Y0 + 2 * SZ_H);
    float* cst = (float*)(pb + XPTOT + SZ_Y0 + 2 * SZ_H + 262144);
    u16* zpg = (u16*)(pb + XPTOT + SZ_Y0 + 2 * SZ_H + 786432);

    const u16 *bxT = arena + off[0], *hf_a = arena + off[1];
    const u16 *wih_l0f = arena + off[2],  *whh_l0f = arena + off[3],  *bih_l0f = arena + off[4],  *bhh_l0f = arena + off[5];
    const u16 *wih_l0b = arena + off[6],  *whh_l0b = arena + off[7],  *bih_l0b = arena + off[8],  *bhh_l0b = arena + off[9];
    const u16 *wih_l1f = arena + off[10], *whh_l1f = arena + off[11], *bih_l1f = arena + off[12], *bhh_l1f = arena + off[13];
    const u16 *wih_l1b = arena + off[14], *whh_l1b = arena + off[15], *bih_l1b = arena + off[16], *bhh_l1b = arena + off[17];
    const u16 *wl1_a = arena + off[18], *wl2_a = arena + off[19], *bl2_a = arena + off[20];

    CvtArgs ca;
    u32 bk = 0;
    for (int i = 0; i < NSEG; ++i) {
        ca.src[i] = d_in[SRC_IDX[i + 1]];
        ca.cnt[i] = CNT21[i + 1];
        ca.off[i] = off[i + 1];
        ca.blk0[i] = bk;
        bk += (CNT21[i + 1] + 2047u) / 2048u;
    }
    prep_k<<<bk + 15000 + 1, 256, 0, stream>>>(ca, d_in[0], d_in[2],
                                               arena, (u16*)(arena + off[0]), flag, zpg, (int)bk);

    // ---- layer 0: pipeline proj(c+1) under lstm(c) ----
    proj_k<200><<<CS * 32, 256, 0, stream>>>(zpg, bxT, wih_l0f, wih_l0b,
        bih_l0f, bhh_l0f, bih_l0b, bhh_l0b, xc_f[0], xc_b[0], CS, 0, (300 - CS) * 4, 0, 300 - CS);
    for (int c = 0; c < NC; ++c) {
        const int par = dbuf ? (c & 1) : 0;
        const int nx  = dbuf ? (par ^ 1) : 0;
        const int tf0 = c * CS, tb0 = 300 - (c + 1) * CS;
        if (!dbuf && c > 0)
            proj_k<200><<<CS * 32, 256, 0, stream>>>(zpg, bxT, wih_l0f, wih_l0b,
                bih_l0f, bhh_l0f, bih_l0b, bhh_l0b, xc_f[0], xc_b[0], CS,
                tf0 * 4, tb0 * 4, tf0, tb0);
        const int dp = dbuf && (c + 1 < NC);
        const int ntf0 = (c + 1) * CS, ntb0 = 300 - (c + 2) * CS;
        fused_k<200><<<256 + (dp ? CS * 32 : 0), 256, 0, stream>>>(zpg,
            xc_f[par], xc_b[par], whh_l0f, whh_l0b, hf_a, y0, y0, hst, cst,
            256, 256, 0, 128, CS, c * CS, tf0, tb0, c == 0, CS,
            bxT, wih_l0f, wih_l0b, bih_l0f, bhh_l0f, bih_l0b, bhh_l0b,
            xc_f[nx], xc_b[nx], ntf0 * 4, ntb0 * 4, ntf0, ntb0);
    }

    // ---- layer 1 ----
    proj_k<256><<<CS * 32, 256, 0, stream>>>(zpg, y0, wih_l1f, wih_l1b,
        bih_l1f, bhh_l1f, bih_l1b, bhh_l1b, xc_f[0], xc_b[0], CS, 0, (300 - CS) * 4, 0, 300 - CS);
    for (int c = 0; c < NC; ++c) {
        const int par = dbuf ? (c & 1) : 0;
        const int nx  = dbuf ? (par ^ 1) : 0;
        const int tf0 = c * CS, tb0 = 300 - (c + 1) * CS;
        if (!dbuf && c > 0)
            proj_k<256><<<CS * 32, 256, 0, stream>>>(zpg, y0, wih_l1f, wih_l1b,
                bih_l1f, bhh_l1f, bih_l1b, bhh_l1b, xc_f[0], xc_b[0], CS,
                tf0 * 4, tb0 * 4, tf0, tb0);
        const int dp = dbuf && (c + 1 < NC);
        const int ntf0 = (c + 1) * CS, ntb0 = 300 - (c + 2) * CS;
        fused_k<256><<<256 + (dp ? CS * 32 : 0), 256, 0, stream>>>(zpg,
            xc_f[par], xc_b[par], whh_l1f, whh_l1b, hf_a, f1, r1, hst, cst,
            128, 128, 0, 0, CS, c * CS, tf0, tb0, c == 0, CS,
            y0, wih_l1f, wih_l1b, bih_l1f, bhh_l1f, bih_l1b, bhh_l1b,
            xc_f[nx], xc_b[nx], ntf0 * 4, ntb0 * 4, ntf0, ntb0);
    }

    headpool_k<<<512, 256, 0, stream>>>(zpg, bxT, wl1_a, f1, r1, hf_a, wl2_a, bl2_a, b_y, d_out, flag);
}